// Round 6
// baseline (270.024 us; speedup 1.0000x reference)
//
#include <hip/hip_runtime.h>
#include <hip/hip_fp16.h>
#include <math.h>

#define NEG_SLOPE 0.2f

__device__ __forceinline__ float lrelu(float x) { return x > 0.f ? x : NEG_SLOPE * x; }

// ---------------------------------------------------------------------------
// K1: h[n, ho] = sum_i x[n,i] * W[i, ho]    (N x 128) @ (128 x 128)
// 64 rows/block; thread = (row, head) owns 32 outputs. W read via broadcast
// global loads (L1/L2-resident, wave-uniform address). LDS only for x tile.
// h stored f16; adi/adj dots computed thread-locally in the epilogue.
// ---------------------------------------------------------------------------
__global__ __launch_bounds__(256) void k_gemm(const float* __restrict__ x,
                                              const float* __restrict__ w,
                                              const float* __restrict__ att,
                                              __half* __restrict__ hout,
                                              float* __restrict__ adi,
                                              float* __restrict__ adj, int N) {
    __shared__ float Xs[64 * 129];
    const int t = threadIdx.x;
    const int row0 = blockIdx.x * 64;

    // stage 64 rows of x (coalesced float4)
    #pragma unroll
    for (int i = 0; i < 8; ++i) {
        int idx = t + 256 * i;              // float4 slot 0..2047
        int r = idx >> 5, c4 = (idx & 31) * 4;
        float4 v = make_float4(0.f, 0.f, 0.f, 0.f);
        if (row0 + r < N) v = *(const float4*)(x + (size_t)(row0 + r) * 128 + c4);
        float* xp = &Xs[r * 129 + c4];
        xp[0] = v.x; xp[1] = v.y; xp[2] = v.z; xp[3] = v.w;
    }
    __syncthreads();

    const int r = t & 63;                   // row within tile (lane)
    const int head = t >> 6;                // 0..3, wave-uniform
    const int c0 = head * 32;

    float acc[32] = {};
    #pragma unroll 4
    for (int k = 0; k < 128; ++k) {
        float xv = Xs[r * 129 + k];         // stride 129: 2 lanes/bank, free
        const float4* wp = (const float4*)(w + (size_t)k * 128 + c0);
        #pragma unroll
        for (int j = 0; j < 8; ++j) {
            float4 b = wp[j];               // wave-uniform addr -> broadcast
            acc[4 * j + 0] += xv * b.x;
            acc[4 * j + 1] += xv * b.y;
            acc[4 * j + 2] += xv * b.z;
            acc[4 * j + 3] += xv * b.w;
        }
    }

    const int row = row0 + r;
    if (row < N) {
        __half2* op = (__half2*)(hout + (size_t)row * 128 + c0);
        #pragma unroll
        for (int j = 0; j < 16; ++j)
            op[j] = __float22half2_rn(make_float2(acc[2 * j], acc[2 * j + 1]));
        float si = 0.f, sj = 0.f;
        #pragma unroll
        for (int j = 0; j < 32; ++j) {
            si += acc[j] * att[head * 64 + j];
            sj += acc[j] * att[head * 64 + 32 + j];
        }
        adi[row * 4 + head] = si;
        adj[row * 4 + head] = sj;
    }
}

// ---------------------------------------------------------------------------
// CSR build: memset -> histogram -> hierarchical scan -> scatter
// ---------------------------------------------------------------------------
__global__ __launch_bounds__(256) void k_hist(const int* __restrict__ ei,
                                              int* __restrict__ cnt, int E) {
    int e = blockIdx.x * blockDim.x + threadIdx.x;
    if (e >= E) return;
    atomicAdd(&cnt[ei[E + e]], 1);
}

__global__ __launch_bounds__(256) void k_partial(const int* __restrict__ cnt,
                                                 int* __restrict__ bsum, int N) {
    __shared__ int s[256];
    int t = threadIdx.x;
    int i = blockIdx.x * 256 + t;
    s[t] = (i < N) ? cnt[i] : 0;
    __syncthreads();
    for (int off = 128; off > 0; off >>= 1) {
        if (t < off) s[t] += s[t + off];
        __syncthreads();
    }
    if (t == 0) bsum[blockIdx.x] = s[0];
}

__global__ __launch_bounds__(256) void k_scanblock(const int* __restrict__ bsum,
                                                   int* __restrict__ boff, int NB) {
    __shared__ int s[256];
    int t = threadIdx.x;
    int chunk = (NB + 255) >> 8;
    int b = t * chunk, e = min(b + chunk, NB);
    int sum = 0;
    for (int i = b; i < e; ++i) sum += bsum[i];
    s[t] = sum;
    __syncthreads();
    for (int off = 1; off < 256; off <<= 1) {
        int v = (t >= off) ? s[t - off] : 0;
        __syncthreads();
        s[t] += v;
        __syncthreads();
    }
    int run = (t == 0) ? 0 : s[t - 1];
    for (int i = b; i < e; ++i) { boff[i] = run; run += bsum[i]; }
}

__global__ __launch_bounds__(256) void k_apply(const int* __restrict__ cnt,
                                               const int* __restrict__ boff,
                                               int* __restrict__ rowoff,
                                               int* __restrict__ cursor, int N) {
    __shared__ int s[256];
    int t = threadIdx.x;
    int i = blockIdx.x * 256 + t;
    int v = (i < N) ? cnt[i] : 0;
    s[t] = v;
    __syncthreads();
    for (int off = 1; off < 256; off <<= 1) {
        int x = (t >= off) ? s[t - off] : 0;
        __syncthreads();
        s[t] += x;
        __syncthreads();
    }
    int excl = s[t] - v + boff[blockIdx.x];
    if (i < N) { rowoff[i] = excl; cursor[i] = excl; }
    if (i == N - 1) rowoff[N] = excl + v;
}

__global__ __launch_bounds__(256) void k_scatter(const int* __restrict__ ei,
                                                 int* __restrict__ cursor,
                                                 int* __restrict__ csr_src, int E) {
    int e = blockIdx.x * blockDim.x + threadIdx.x;
    if (e >= E) return;
    int dst = ei[E + e];
    int pos = atomicAdd(&cursor[dst], 1);
    csr_src[pos] = ei[e];
}

// ---------------------------------------------------------------------------
// K3: one wave per node, single pass. 4 edges unrolled per iteration with
// fully independent load chains (MLP), scalar broadcast adj loads.
// ---------------------------------------------------------------------------
__global__ __launch_bounds__(256) void k_node(const int* __restrict__ rowoff,
                                              const int* __restrict__ csr_src,
                                              const __half2* __restrict__ h2,
                                              const float* __restrict__ adi,
                                              const float* __restrict__ adjf,
                                              const float* __restrict__ bias,
                                              float* __restrict__ out, int N) {
    int node = (blockIdx.x * blockDim.x + threadIdx.x) >> 6;
    if (node >= N) return;
    const int lane = threadIdx.x & 63;
    const int head = lane >> 4;

    const int beg = rowoff[node];
    const int deg = rowoff[node + 1] - beg;
    const float ai = adi[node * 4 + head];

    float acc0 = 0.f, acc1 = 0.f, dsum = 0.f;

    int i = 0;
    for (; i + 4 <= deg; i += 4) {
        int s0 = csr_src[beg + i + 0];
        int s1 = csr_src[beg + i + 1];
        int s2 = csr_src[beg + i + 2];
        int s3 = csr_src[beg + i + 3];
        float aj0 = adjf[s0 * 4 + head];
        float aj1 = adjf[s1 * 4 + head];
        float aj2 = adjf[s2 * 4 + head];
        float aj3 = adjf[s3 * 4 + head];
        float2 h0 = __half22float2(h2[(size_t)s0 * 64 + lane]);
        float2 h1 = __half22float2(h2[(size_t)s1 * 64 + lane]);
        float2 hv2 = __half22float2(h2[(size_t)s2 * 64 + lane]);
        float2 hv3 = __half22float2(h2[(size_t)s3 * 64 + lane]);

        float e0 = __expf(lrelu(ai + aj0));
        float e1 = __expf(lrelu(ai + aj1));
        float e2 = __expf(lrelu(ai + aj2));
        float e3 = __expf(lrelu(ai + aj3));
        dsum += (e0 + e1) + (e2 + e3);
        acc0 += h0.x * e0 + h1.x * e1 + hv2.x * e2 + hv3.x * e3;
        acc1 += h0.y * e0 + h1.y * e1 + hv2.y * e2 + hv3.y * e3;
    }
    for (; i < deg; ++i) {
        int src = csr_src[beg + i];
        float aj = adjf[src * 4 + head];
        float ex = __expf(lrelu(ai + aj));
        dsum += ex;
        float2 hv = __half22float2(h2[(size_t)src * 64 + lane]);
        acc0 += hv.x * ex;
        acc1 += hv.y * ex;
    }

    float inv = 1.f / (dsum + 1e-16f);
    float2 bv = ((const float2*)bias)[lane];
    ((float2*)out)[(size_t)node * 64 + lane] =
        make_float2(acc0 * inv + bv.x, acc1 * inv + bv.y);
}

extern "C" void kernel_launch(void* const* d_in, const int* in_sizes, int n_in,
                              void* d_out, int out_size, void* d_ws, size_t ws_size,
                              hipStream_t stream) {
    const float* x    = (const float*)d_in[0];
    const int*   ei   = (const int*)d_in[1];
    const float* w    = (const float*)d_in[2];
    const float* att  = (const float*)d_in[3];
    const float* bias = (const float*)d_in[4];

    const int N = in_sizes[0] / 128;   // 50000
    const int E = in_sizes[1] / 2;     // 800000

    float* out = (float*)d_out;
    char*  wsb = (char*)d_ws;

    __half* h   = (__half*)wsb;                                // N*128 f16
    float*  adi = (float*)(wsb + (size_t)N * 128 * 2);         // N*4 f
    float*  adj = adi + (size_t)N * 4;                         // N*4 f
    int* cnt     = (int*)(adj + (size_t)N * 4);                // N
    int* rowoff  = cnt + N;                                    // N+1
    int* cursor  = rowoff + (N + 1);                           // N
    int* csr_src = cursor + N;                                 // E
    int* bsum    = csr_src + E;                                // NB
    int* boff    = bsum + 4096;                                // NB

    const int NB = (N + 255) / 256;

    k_gemm<<<(N + 63) / 64, 256, 0, stream>>>(x, w, att, h, adi, adj, N);

    hipMemsetAsync(cnt, 0, (size_t)N * sizeof(int), stream);
    k_hist<<<(E + 255) / 256, 256, 0, stream>>>(ei, cnt, E);
    k_partial<<<NB, 256, 0, stream>>>(cnt, bsum, N);
    k_scanblock<<<1, 256, 0, stream>>>(bsum, boff, NB);
    k_apply<<<NB, 256, 0, stream>>>(cnt, boff, rowoff, cursor, N);
    k_scatter<<<(E + 255) / 256, 256, 0, stream>>>(ei, cursor, csr_src, E);

    {
        long long total = (long long)N * 64;
        int blocks = (int)((total + 255) / 256);
        k_node<<<blocks, 256, 0, stream>>>(rowoff, csr_src, (const __half2*)h,
                                           adi, adj, bias, out, N);
    }
}

// Round 7
// 167.882 us; speedup vs baseline: 1.6084x; 1.6084x over previous
//
#include <hip/hip_runtime.h>
#include <hip/hip_fp16.h>
#include <math.h>

#define NEG_SLOPE 0.2f

typedef __attribute__((ext_vector_type(8))) short bf16x8;
typedef __attribute__((ext_vector_type(4))) short short4v;
typedef __attribute__((ext_vector_type(4))) float f32x4;

__device__ __forceinline__ float lrelu(float x) { return x > 0.f ? x : NEG_SLOPE * x; }

__device__ __forceinline__ short f2bf(float f) {   // RNE f32 -> bf16
    unsigned u = __float_as_uint(f);
    u += 0x7fff + ((u >> 16) & 1);
    return (short)(u >> 16);
}

// ---------------------------------------------------------------------------
// K1: h = x @ W via MFMA bf16. Block = 128 rows x 128 cols, K = 128 one-shot.
// LDS: As = x tile bf16 [row][k], Bs = W^T bf16 [col][k]; both XOR-swizzled
// (short-index ^= (row&7)<<3) so staging writes AND fragment ds_read_b128
// are conflict-free (T2 / G4). 4 waves: wave w owns rows w*32..w*32+31.
// ---------------------------------------------------------------------------
__global__ __launch_bounds__(256) void k_gemm(const float* __restrict__ x,
                                              const float* __restrict__ w,
                                              __half* __restrict__ hout, int N) {
    __shared__ short As[16384];
    __shared__ short Bs[16384];
    const int t = threadIdx.x;
    const int row0 = blockIdx.x * 128;

    // stage x -> As (coalesced float4 reads, bf16 convert, swizzled ds_write_b64)
    #pragma unroll
    for (int i = 0; i < 16; ++i) {
        int idx = t + 256 * i;              // float4 slot 0..4095
        int r = idx >> 5, c4 = (idx & 31) * 4;
        float4 v = make_float4(0.f, 0.f, 0.f, 0.f);
        if (row0 + r < N) v = *(const float4*)(x + (size_t)(row0 + r) * 128 + c4);
        short4v s;
        s.x = f2bf(v.x); s.y = f2bf(v.y); s.z = f2bf(v.z); s.w = f2bf(v.w);
        *(short4v*)&As[(r * 128 + c4) ^ ((r & 7) << 3)] = s;
    }
    // stage W^T -> Bs (column reads, L2-resident 64KB)
    {
        int c = t & 127, kh = (t >> 7) * 64;
        for (int kb = 0; kb < 16; ++kb) {
            int k = kh + kb * 4;
            short4v s;
            s.x = f2bf(w[(size_t)(k + 0) * 128 + c]);
            s.y = f2bf(w[(size_t)(k + 1) * 128 + c]);
            s.z = f2bf(w[(size_t)(k + 2) * 128 + c]);
            s.w = f2bf(w[(size_t)(k + 3) * 128 + c]);
            *(short4v*)&Bs[(c * 128 + k) ^ ((c & 7) << 3)] = s;
        }
    }
    __syncthreads();

    const int wv = t >> 6, lane = t & 63;
    const int lr = lane & 15, kg = lane >> 4;

    f32x4 acc[2][8];
    #pragma unroll
    for (int m = 0; m < 2; ++m)
        #pragma unroll
        for (int n = 0; n < 8; ++n) acc[m][n] = (f32x4){0.f, 0.f, 0.f, 0.f};

    #pragma unroll
    for (int kk = 0; kk < 4; ++kk) {
        const int k0 = kk * 32 + kg * 8;
        bf16x8 a[2], b[8];
        #pragma unroll
        for (int m = 0; m < 2; ++m) {
            int r = wv * 32 + m * 16 + lr;
            a[m] = *(const bf16x8*)&As[(r * 128 + k0) ^ ((r & 7) << 3)];
        }
        #pragma unroll
        for (int n = 0; n < 8; ++n) {
            int c = n * 16 + lr;
            b[n] = *(const bf16x8*)&Bs[(c * 128 + k0) ^ ((c & 7) << 3)];
        }
        #pragma unroll
        for (int m = 0; m < 2; ++m)
            #pragma unroll
            for (int n = 0; n < 8; ++n)
                acc[m][n] = __builtin_amdgcn_mfma_f32_16x16x32_bf16(a[m], b[n], acc[m][n], 0, 0, 0);
    }

    // epilogue: C/D frag is col=lane&15, row=(lane>>4)*4+reg
    #pragma unroll
    for (int m = 0; m < 2; ++m) {
        #pragma unroll
        for (int reg = 0; reg < 4; ++reg) {
            int r = row0 + wv * 32 + m * 16 + kg * 4 + reg;
            if (r < N) {
                __half* hp = hout + (size_t)r * 128 + lr;
                #pragma unroll
                for (int n = 0; n < 8; ++n)
                    hp[n * 16] = __float2half(acc[m][n][reg]);
            }
        }
    }
}

// ---------------------------------------------------------------------------
// K2: per-node attention dots from f16 h (12.8MB read, ~3us)
// ---------------------------------------------------------------------------
__global__ __launch_bounds__(256) void k_adot(const __half2* __restrict__ h2,
                                              const float* __restrict__ att,
                                              float* __restrict__ adi,
                                              float* __restrict__ adj, int N) {
    int tid = blockIdx.x * blockDim.x + threadIdx.x;
    if (tid >= N * 4) return;
    int n = tid >> 2, head = tid & 3;
    const __half2* hp = h2 + (size_t)n * 64 + head * 16;
    const float* aw = att + head * 64;
    float si = 0.f, sj = 0.f;
    #pragma unroll
    for (int o = 0; o < 16; ++o) {
        float2 hv = __half22float2(hp[o]);
        si += hv.x * aw[2 * o] + hv.y * aw[2 * o + 1];
        sj += hv.x * aw[32 + 2 * o] + hv.y * aw[32 + 2 * o + 1];
    }
    adi[tid] = si;
    adj[tid] = sj;
}

// ---------------------------------------------------------------------------
// CSR build: memset -> histogram -> hierarchical scan -> scatter
// ---------------------------------------------------------------------------
__global__ __launch_bounds__(256) void k_hist(const int* __restrict__ ei,
                                              int* __restrict__ cnt, int E) {
    int e = blockIdx.x * blockDim.x + threadIdx.x;
    if (e >= E) return;
    atomicAdd(&cnt[ei[E + e]], 1);
}

__global__ __launch_bounds__(256) void k_partial(const int* __restrict__ cnt,
                                                 int* __restrict__ bsum, int N) {
    __shared__ int s[256];
    int t = threadIdx.x;
    int i = blockIdx.x * 256 + t;
    s[t] = (i < N) ? cnt[i] : 0;
    __syncthreads();
    for (int off = 128; off > 0; off >>= 1) {
        if (t < off) s[t] += s[t + off];
        __syncthreads();
    }
    if (t == 0) bsum[blockIdx.x] = s[0];
}

__global__ __launch_bounds__(256) void k_scanblock(const int* __restrict__ bsum,
                                                   int* __restrict__ boff, int NB) {
    __shared__ int s[256];
    int t = threadIdx.x;
    int chunk = (NB + 255) >> 8;
    int b = t * chunk, e = min(b + chunk, NB);
    int sum = 0;
    for (int i = b; i < e; ++i) sum += bsum[i];
    s[t] = sum;
    __syncthreads();
    for (int off = 1; off < 256; off <<= 1) {
        int v = (t >= off) ? s[t - off] : 0;
        __syncthreads();
        s[t] += v;
        __syncthreads();
    }
    int run = (t == 0) ? 0 : s[t - 1];
    for (int i = b; i < e; ++i) { boff[i] = run; run += bsum[i]; }
}

__global__ __launch_bounds__(256) void k_apply(const int* __restrict__ cnt,
                                               const int* __restrict__ boff,
                                               int* __restrict__ rowoff,
                                               int* __restrict__ cursor, int N) {
    __shared__ int s[256];
    int t = threadIdx.x;
    int i = blockIdx.x * 256 + t;
    int v = (i < N) ? cnt[i] : 0;
    s[t] = v;
    __syncthreads();
    for (int off = 1; off < 256; off <<= 1) {
        int x = (t >= off) ? s[t - off] : 0;
        __syncthreads();
        s[t] += x;
        __syncthreads();
    }
    int excl = s[t] - v + boff[blockIdx.x];
    if (i < N) { rowoff[i] = excl; cursor[i] = excl; }
    if (i == N - 1) rowoff[N] = excl + v;
}

__global__ __launch_bounds__(256) void k_scatter(const int* __restrict__ ei,
                                                 int* __restrict__ cursor,
                                                 int* __restrict__ csr_src, int E) {
    int e = blockIdx.x * blockDim.x + threadIdx.x;
    if (e >= E) return;
    int dst = ei[E + e];
    int pos = atomicAdd(&cursor[dst], 1);
    csr_src[pos] = ei[e];
}

// ---------------------------------------------------------------------------
// K3: one wave per node, single pass, 4-edge unroll (independent MLP chains)
// ---------------------------------------------------------------------------
__global__ __launch_bounds__(256) void k_node(const int* __restrict__ rowoff,
                                              const int* __restrict__ csr_src,
                                              const __half2* __restrict__ h2,
                                              const float* __restrict__ adi,
                                              const float* __restrict__ adjf,
                                              const float* __restrict__ bias,
                                              float* __restrict__ out, int N) {
    int node = (blockIdx.x * blockDim.x + threadIdx.x) >> 6;
    if (node >= N) return;
    const int lane = threadIdx.x & 63;
    const int head = lane >> 4;

    const int beg = rowoff[node];
    const int deg = rowoff[node + 1] - beg;
    const float ai = adi[node * 4 + head];

    float acc0 = 0.f, acc1 = 0.f, dsum = 0.f;

    int i = 0;
    for (; i + 4 <= deg; i += 4) {
        int s0 = csr_src[beg + i + 0];
        int s1 = csr_src[beg + i + 1];
        int s2 = csr_src[beg + i + 2];
        int s3 = csr_src[beg + i + 3];
        float aj0 = adjf[s0 * 4 + head];
        float aj1 = adjf[s1 * 4 + head];
        float aj2 = adjf[s2 * 4 + head];
        float aj3 = adjf[s3 * 4 + head];
        float2 h0 = __half22float2(h2[(size_t)s0 * 64 + lane]);
        float2 h1 = __half22float2(h2[(size_t)s1 * 64 + lane]);
        float2 hv2 = __half22float2(h2[(size_t)s2 * 64 + lane]);
        float2 hv3 = __half22float2(h2[(size_t)s3 * 64 + lane]);

        float e0 = __expf(lrelu(ai + aj0));
        float e1 = __expf(lrelu(ai + aj1));
        float e2 = __expf(lrelu(ai + aj2));
        float e3 = __expf(lrelu(ai + aj3));
        dsum += (e0 + e1) + (e2 + e3);
        acc0 += h0.x * e0 + h1.x * e1 + hv2.x * e2 + hv3.x * e3;
        acc1 += h0.y * e0 + h1.y * e1 + hv2.y * e2 + hv3.y * e3;
    }
    for (; i < deg; ++i) {
        int src = csr_src[beg + i];
        float aj = adjf[src * 4 + head];
        float ex = __expf(lrelu(ai + aj));
        dsum += ex;
        float2 hv = __half22float2(h2[(size_t)src * 64 + lane]);
        acc0 += hv.x * ex;
        acc1 += hv.y * ex;
    }

    float inv = 1.f / (dsum + 1e-16f);
    float2 bv = ((const float2*)bias)[lane];
    ((float2*)out)[(size_t)node * 64 + lane] =
        make_float2(acc0 * inv + bv.x, acc1 * inv + bv.y);
}

extern "C" void kernel_launch(void* const* d_in, const int* in_sizes, int n_in,
                              void* d_out, int out_size, void* d_ws, size_t ws_size,
                              hipStream_t stream) {
    const float* x    = (const float*)d_in[0];
    const int*   ei   = (const int*)d_in[1];
    const float* w    = (const float*)d_in[2];
    const float* att  = (const float*)d_in[3];
    const float* bias = (const float*)d_in[4];

    const int N = in_sizes[0] / 128;   // 50000
    const int E = in_sizes[1] / 2;     // 800000

    float* out = (float*)d_out;
    char*  wsb = (char*)d_ws;

    __half* h   = (__half*)wsb;                                // N*128 f16
    float*  adi = (float*)(wsb + (size_t)N * 128 * 2);         // N*4 f
    float*  adj = adi + (size_t)N * 4;                         // N*4 f
    int* cnt     = (int*)(adj + (size_t)N * 4);                // N
    int* rowoff  = cnt + N;                                    // N+1
    int* cursor  = rowoff + (N + 1);                           // N
    int* csr_src = cursor + N;                                 // E
    int* bsum    = csr_src + E;                                // NB
    int* boff    = bsum + 4096;                                // NB

    const int NB = (N + 255) / 256;

    k_gemm<<<(N + 127) / 128, 256, 0, stream>>>(x, w, h, N);
    k_adot<<<(N * 4 + 255) / 256, 256, 0, stream>>>((const __half2*)h, att, adi, adj, N);

    hipMemsetAsync(cnt, 0, (size_t)N * sizeof(int), stream);
    k_hist<<<(E + 255) / 256, 256, 0, stream>>>(ei, cnt, E);
    k_partial<<<NB, 256, 0, stream>>>(cnt, bsum, N);
    k_scanblock<<<1, 256, 0, stream>>>(bsum, boff, NB);
    k_apply<<<NB, 256, 0, stream>>>(cnt, boff, rowoff, cursor, N);
    k_scatter<<<(E + 255) / 256, 256, 0, stream>>>(ei, cursor, csr_src, E);

    {
        long long total = (long long)N * 64;
        int blocks = (int)((total + 255) / 256);
        k_node<<<blocks, 256, 0, stream>>>(rowoff, csr_src, (const __half2*)h,
                                           adi, adj, bias, out, N);
    }
}

// Round 8
// 111.087 us; speedup vs baseline: 2.4307x; 1.5113x over previous
//
#include <hip/hip_runtime.h>
#include <hip/hip_fp16.h>
#include <math.h>

#define NEG_SLOPE 0.2f

typedef __attribute__((ext_vector_type(8))) short bf16x8;
typedef __attribute__((ext_vector_type(4))) short short4v;
typedef __attribute__((ext_vector_type(4))) float f32x4;

__device__ __forceinline__ float lrelu(float x) { return x > 0.f ? x : NEG_SLOPE * x; }

__device__ __forceinline__ short f2bf(float f) {   // RNE f32 -> bf16
    unsigned u = __float_as_uint(f);
    u += 0x7fff + ((u >> 16) & 1);
    return (short)(u >> 16);
}

// ---------------------------------------------------------------------------
// K1: h = x @ W via MFMA bf16. Block = 128x128 tile, K = 128 one-shot.
// ---------------------------------------------------------------------------
__global__ __launch_bounds__(256) void k_gemm(const float* __restrict__ x,
                                              const float* __restrict__ w,
                                              __half* __restrict__ hout, int N) {
    __shared__ short As[16384];
    __shared__ short Bs[16384];
    const int t = threadIdx.x;
    const int row0 = blockIdx.x * 128;

    #pragma unroll
    for (int i = 0; i < 16; ++i) {
        int idx = t + 256 * i;
        int r = idx >> 5, c4 = (idx & 31) * 4;
        float4 v = make_float4(0.f, 0.f, 0.f, 0.f);
        if (row0 + r < N) v = *(const float4*)(x + (size_t)(row0 + r) * 128 + c4);
        short4v s;
        s.x = f2bf(v.x); s.y = f2bf(v.y); s.z = f2bf(v.z); s.w = f2bf(v.w);
        *(short4v*)&As[(r * 128 + c4) ^ ((r & 7) << 3)] = s;
    }
    {
        int c = t & 127, kh = (t >> 7) * 64;
        for (int kb = 0; kb < 16; ++kb) {
            int k = kh + kb * 4;
            short4v s;
            s.x = f2bf(w[(size_t)(k + 0) * 128 + c]);
            s.y = f2bf(w[(size_t)(k + 1) * 128 + c]);
            s.z = f2bf(w[(size_t)(k + 2) * 128 + c]);
            s.w = f2bf(w[(size_t)(k + 3) * 128 + c]);
            *(short4v*)&Bs[(c * 128 + k) ^ ((c & 7) << 3)] = s;
        }
    }
    __syncthreads();

    const int wv = t >> 6, lane = t & 63;
    const int lr = lane & 15, kg = lane >> 4;

    f32x4 acc[2][8];
    #pragma unroll
    for (int m = 0; m < 2; ++m)
        #pragma unroll
        for (int n = 0; n < 8; ++n) acc[m][n] = (f32x4){0.f, 0.f, 0.f, 0.f};

    #pragma unroll
    for (int kk = 0; kk < 4; ++kk) {
        const int k0 = kk * 32 + kg * 8;
        bf16x8 a[2], b[8];
        #pragma unroll
        for (int m = 0; m < 2; ++m) {
            int r = wv * 32 + m * 16 + lr;
            a[m] = *(const bf16x8*)&As[(r * 128 + k0) ^ ((r & 7) << 3)];
        }
        #pragma unroll
        for (int n = 0; n < 8; ++n) {
            int c = n * 16 + lr;
            b[n] = *(const bf16x8*)&Bs[(c * 128 + k0) ^ ((c & 7) << 3)];
        }
        #pragma unroll
        for (int m = 0; m < 2; ++m)
            #pragma unroll
            for (int n = 0; n < 8; ++n)
                acc[m][n] = __builtin_amdgcn_mfma_f32_16x16x32_bf16(a[m], b[n], acc[m][n], 0, 0, 0);
    }

    #pragma unroll
    for (int m = 0; m < 2; ++m) {
        #pragma unroll
        for (int reg = 0; reg < 4; ++reg) {
            int r = row0 + wv * 32 + m * 16 + kg * 4 + reg;
            if (r < N) {
                __half* hp = hout + (size_t)r * 128 + lr;
                #pragma unroll
                for (int n = 0; n < 8; ++n)
                    hp[n * 16] = __float2half(acc[m][n][reg]);
            }
        }
    }
}

// ---------------------------------------------------------------------------
// K2: per-node attention dots from f16 h
// ---------------------------------------------------------------------------
__global__ __launch_bounds__(256) void k_adot(const __half2* __restrict__ h2,
                                              const float* __restrict__ att,
                                              float* __restrict__ adi,
                                              float* __restrict__ adj, int N) {
    int tid = blockIdx.x * blockDim.x + threadIdx.x;
    if (tid >= N * 4) return;
    int n = tid >> 2, head = tid & 3;
    const __half2* hp = h2 + (size_t)n * 64 + head * 16;
    const float* aw = att + head * 64;
    float si = 0.f, sj = 0.f;
    #pragma unroll
    for (int o = 0; o < 16; ++o) {
        float2 hv = __half22float2(hp[o]);
        si += hv.x * aw[2 * o] + hv.y * aw[2 * o + 1];
        sj += hv.x * aw[32 + 2 * o] + hv.y * aw[32 + 2 * o + 1];
    }
    adi[tid] = si;
    adj[tid] = sj;
}

// ---------------------------------------------------------------------------
// CSR build, bucketed counting sort. Bucket = dst>>8 (256 nodes each).
// k_bin: partition edges into per-bucket bins, packed (dstLow<<24 | src).
// ---------------------------------------------------------------------------
__global__ __launch_bounds__(256) void k_bin(const int* __restrict__ ei,
                                             int* __restrict__ gcur,
                                             unsigned* __restrict__ bins,
                                             int E, int nbkt, int cap) {
    __shared__ int lcnt[256];
    __shared__ int lbase[256];
    const int t = threadIdx.x;
    if (t < nbkt) lcnt[t] = 0;
    __syncthreads();

    const int e0 = blockIdx.x * 2048;
    const int ne = min(2048, E - e0);

    int bkt[8], rank[8];
    unsigned pk[8];
    #pragma unroll
    for (int k = 0; k < 8; ++k) {
        int idx = t + k * 256;
        if (idx < ne) {
            int e = e0 + idx;
            int src = ei[e], dst = ei[E + e];
            int b = dst >> 8;
            bkt[k] = b;
            pk[k] = ((unsigned)(dst & 255) << 24) | (unsigned)src;
            rank[k] = atomicAdd(&lcnt[b], 1);
        } else bkt[k] = -1;
    }
    __syncthreads();
    if (t < nbkt && lcnt[t] > 0) lbase[t] = atomicAdd(&gcur[t], lcnt[t]);
    __syncthreads();
    #pragma unroll
    for (int k = 0; k < 8; ++k) {
        if (bkt[k] >= 0)
            bins[(size_t)bkt[k] * cap + lbase[bkt[k]] + rank[k]] = pk[k];
    }
}

// exclusive scan of nbkt bucket sizes -> boff[0..nbkt]
__global__ __launch_bounds__(256) void k_bscan(const int* __restrict__ gcur,
                                               int* __restrict__ boff, int nbkt) {
    __shared__ int s[256];
    int t = threadIdx.x;
    int v = (t < nbkt) ? gcur[t] : 0;
    s[t] = v;
    __syncthreads();
    for (int off = 1; off < 256; off <<= 1) {
        int u = (t >= off) ? s[t - off] : 0;
        __syncthreads();
        s[t] += u;
        __syncthreads();
    }
    if (t < nbkt) boff[t] = s[t] - v;
    if (t == nbkt - 1) boff[nbkt] = s[t];
}

// one block per bucket: LDS histogram + scan -> rowoff; LDS cursors -> csr.
// All csr writes land in this block's contiguous region (no line sharing).
__global__ __launch_bounds__(256) void k_bucket(const unsigned* __restrict__ bins,
                                                const int* __restrict__ gcur,
                                                const int* __restrict__ boff,
                                                int* __restrict__ rowoff,
                                                int* __restrict__ csr_src,
                                                int N, int cap) {
    __shared__ int cnt[256];
    __shared__ int scn[256];
    __shared__ int cur[256];
    const int b = blockIdx.x, t = threadIdx.x;
    const int sz = gcur[b];
    const int base = boff[b];
    const unsigned* myb = bins + (size_t)b * cap;

    cnt[t] = 0;
    __syncthreads();
    for (int i = t; i < sz; i += 256) atomicAdd(&cnt[myb[i] >> 24], 1);
    __syncthreads();
    int v = cnt[t];
    scn[t] = v;
    __syncthreads();
    for (int off = 1; off < 256; off <<= 1) {
        int u = (t >= off) ? scn[t - off] : 0;
        __syncthreads();
        scn[t] += u;
        __syncthreads();
    }
    int excl = scn[t] - v;
    int node = b * 256 + t;
    if (node < N) rowoff[node] = base + excl;
    if (node == N - 1) rowoff[N] = base + excl + v;
    cur[t] = excl;
    __syncthreads();
    for (int i = t; i < sz; i += 256) {
        unsigned p = myb[i];
        int pos = atomicAdd(&cur[p >> 24], 1);
        csr_src[base + pos] = (int)(p & 0xFFFFFFu);
    }
}

// ---------------------------------------------------------------------------
// K3: one wave per node, single pass, 4-edge unroll (independent MLP chains)
// ---------------------------------------------------------------------------
__global__ __launch_bounds__(256) void k_node(const int* __restrict__ rowoff,
                                              const int* __restrict__ csr_src,
                                              const __half2* __restrict__ h2,
                                              const float* __restrict__ adi,
                                              const float* __restrict__ adjf,
                                              const float* __restrict__ bias,
                                              float* __restrict__ out, int N) {
    int node = (blockIdx.x * blockDim.x + threadIdx.x) >> 6;
    if (node >= N) return;
    const int lane = threadIdx.x & 63;
    const int head = lane >> 4;

    const int beg = rowoff[node];
    const int deg = rowoff[node + 1] - beg;
    const float ai = adi[node * 4 + head];

    float acc0 = 0.f, acc1 = 0.f, dsum = 0.f;

    int i = 0;
    for (; i + 4 <= deg; i += 4) {
        int s0 = csr_src[beg + i + 0];
        int s1 = csr_src[beg + i + 1];
        int s2 = csr_src[beg + i + 2];
        int s3 = csr_src[beg + i + 3];
        float aj0 = adjf[s0 * 4 + head];
        float aj1 = adjf[s1 * 4 + head];
        float aj2 = adjf[s2 * 4 + head];
        float aj3 = adjf[s3 * 4 + head];
        float2 h0 = __half22float2(h2[(size_t)s0 * 64 + lane]);
        float2 h1 = __half22float2(h2[(size_t)s1 * 64 + lane]);
        float2 hv2 = __half22float2(h2[(size_t)s2 * 64 + lane]);
        float2 hv3 = __half22float2(h2[(size_t)s3 * 64 + lane]);

        float e0 = __expf(lrelu(ai + aj0));
        float e1 = __expf(lrelu(ai + aj1));
        float e2 = __expf(lrelu(ai + aj2));
        float e3 = __expf(lrelu(ai + aj3));
        dsum += (e0 + e1) + (e2 + e3);
        acc0 += h0.x * e0 + h1.x * e1 + hv2.x * e2 + hv3.x * e3;
        acc1 += h0.y * e0 + h1.y * e1 + hv2.y * e2 + hv3.y * e3;
    }
    for (; i < deg; ++i) {
        int src = csr_src[beg + i];
        float aj = adjf[src * 4 + head];
        float ex = __expf(lrelu(ai + aj));
        dsum += ex;
        float2 hv = __half22float2(h2[(size_t)src * 64 + lane]);
        acc0 += hv.x * ex;
        acc1 += hv.y * ex;
    }

    float inv = 1.f / (dsum + 1e-16f);
    float2 bv = ((const float2*)bias)[lane];
    ((float2*)out)[(size_t)node * 64 + lane] =
        make_float2(acc0 * inv + bv.x, acc1 * inv + bv.y);
}

extern "C" void kernel_launch(void* const* d_in, const int* in_sizes, int n_in,
                              void* d_out, int out_size, void* d_ws, size_t ws_size,
                              hipStream_t stream) {
    const float* x    = (const float*)d_in[0];
    const int*   ei   = (const int*)d_in[1];
    const float* w    = (const float*)d_in[2];
    const float* att  = (const float*)d_in[3];
    const float* bias = (const float*)d_in[4];

    const int N = in_sizes[0] / 128;   // 50000
    const int E = in_sizes[1] / 2;     // 800000

    const int NBKT = (N + 255) >> 8;   // 196
    const int CAP  = 8192;             // mean ~4096, +64 sigma headroom

    float* out = (float*)d_out;
    char*  wsb = (char*)d_ws;

    __half* h   = (__half*)wsb;                                // N*128 f16
    float*  adi = (float*)(wsb + (size_t)N * 128 * 2);         // N*4 f
    float*  adj = adi + (size_t)N * 4;                         // N*4 f
    int* rowoff   = (int*)(adj + (size_t)N * 4);               // N+1
    int* csr_src  = rowoff + (N + 1);                          // E
    int* gcur     = csr_src + E;                               // NBKT
    int* boff     = gcur + 256;                                // NBKT+1
    unsigned* bins = (unsigned*)(boff + 257);                  // NBKT*CAP

    k_gemm<<<(N + 127) / 128, 256, 0, stream>>>(x, w, h, N);
    k_adot<<<(N * 4 + 255) / 256, 256, 0, stream>>>((const __half2*)h, att, adi, adj, N);

    hipMemsetAsync(gcur, 0, 256 * sizeof(int), stream);
    k_bin<<<(E + 2047) / 2048, 256, 0, stream>>>(ei, gcur, bins, E, NBKT, CAP);
    k_bscan<<<1, 256, 0, stream>>>(gcur, boff, NBKT);
    k_bucket<<<NBKT, 256, 0, stream>>>(bins, gcur, boff, rowoff, csr_src, N, CAP);

    {
        long long total = (long long)N * 64;
        int blocks = (int)((total + 255) / 256);
        k_node<<<blocks, 256, 0, stream>>>(rowoff, csr_src, (const __half2*)h,
                                           adi, adj, bias, out, N);
    }
}

// Round 9
// 105.103 us; speedup vs baseline: 2.5691x; 1.0569x over previous
//
#include <hip/hip_runtime.h>
#include <hip/hip_fp16.h>
#include <math.h>

#define NEG_SLOPE 0.2f

typedef __attribute__((ext_vector_type(8))) short bf16x8;
typedef __attribute__((ext_vector_type(4))) short short4v;
typedef __attribute__((ext_vector_type(4))) float f32x4;

__device__ __forceinline__ float lrelu(float x) { return x > 0.f ? x : NEG_SLOPE * x; }

__device__ __forceinline__ short f2bf(float f) {   // RNE f32 -> bf16
    unsigned u = __float_as_uint(f);
    u += 0x7fff + ((u >> 16) & 1);
    return (short)(u >> 16);
}

// ---------------------------------------------------------------------------
// K1: h = x @ W via MFMA bf16. Block = 128x128 tile, K = 128 one-shot.
// ---------------------------------------------------------------------------
__global__ __launch_bounds__(256) void k_gemm(const float* __restrict__ x,
                                              const float* __restrict__ w,
                                              __half* __restrict__ hout, int N) {
    __shared__ short As[16384];
    __shared__ short Bs[16384];
    const int t = threadIdx.x;
    const int row0 = blockIdx.x * 128;

    #pragma unroll
    for (int i = 0; i < 16; ++i) {
        int idx = t + 256 * i;
        int r = idx >> 5, c4 = (idx & 31) * 4;
        float4 v = make_float4(0.f, 0.f, 0.f, 0.f);
        if (row0 + r < N) v = *(const float4*)(x + (size_t)(row0 + r) * 128 + c4);
        short4v s;
        s.x = f2bf(v.x); s.y = f2bf(v.y); s.z = f2bf(v.z); s.w = f2bf(v.w);
        *(short4v*)&As[(r * 128 + c4) ^ ((r & 7) << 3)] = s;
    }
    {
        int c = t & 127, kh = (t >> 7) * 64;
        for (int kb = 0; kb < 16; ++kb) {
            int k = kh + kb * 4;
            short4v s;
            s.x = f2bf(w[(size_t)(k + 0) * 128 + c]);
            s.y = f2bf(w[(size_t)(k + 1) * 128 + c]);
            s.z = f2bf(w[(size_t)(k + 2) * 128 + c]);
            s.w = f2bf(w[(size_t)(k + 3) * 128 + c]);
            *(short4v*)&Bs[(c * 128 + k) ^ ((c & 7) << 3)] = s;
        }
    }
    __syncthreads();

    const int wv = t >> 6, lane = t & 63;
    const int lr = lane & 15, kg = lane >> 4;

    f32x4 acc[2][8];
    #pragma unroll
    for (int m = 0; m < 2; ++m)
        #pragma unroll
        for (int n = 0; n < 8; ++n) acc[m][n] = (f32x4){0.f, 0.f, 0.f, 0.f};

    #pragma unroll
    for (int kk = 0; kk < 4; ++kk) {
        const int k0 = kk * 32 + kg * 8;
        bf16x8 a[2], b[8];
        #pragma unroll
        for (int m = 0; m < 2; ++m) {
            int r = wv * 32 + m * 16 + lr;
            a[m] = *(const bf16x8*)&As[(r * 128 + k0) ^ ((r & 7) << 3)];
        }
        #pragma unroll
        for (int n = 0; n < 8; ++n) {
            int c = n * 16 + lr;
            b[n] = *(const bf16x8*)&Bs[(c * 128 + k0) ^ ((c & 7) << 3)];
        }
        #pragma unroll
        for (int m = 0; m < 2; ++m)
            #pragma unroll
            for (int n = 0; n < 8; ++n)
                acc[m][n] = __builtin_amdgcn_mfma_f32_16x16x32_bf16(a[m], b[n], acc[m][n], 0, 0, 0);
    }

    #pragma unroll
    for (int m = 0; m < 2; ++m) {
        #pragma unroll
        for (int reg = 0; reg < 4; ++reg) {
            int r = row0 + wv * 32 + m * 16 + kg * 4 + reg;
            if (r < N) {
                __half* hp = hout + (size_t)r * 128 + lr;
                #pragma unroll
                for (int n = 0; n < 8; ++n)
                    hp[n * 16] = __float2half(acc[m][n][reg]);
            }
        }
    }
}

// ---------------------------------------------------------------------------
// K2: per-node attention dots from f16 h
// ---------------------------------------------------------------------------
__global__ __launch_bounds__(256) void k_adot(const __half2* __restrict__ h2,
                                              const float* __restrict__ att,
                                              float* __restrict__ adi,
                                              float* __restrict__ adj, int N) {
    int tid = blockIdx.x * blockDim.x + threadIdx.x;
    if (tid >= N * 4) return;
    int n = tid >> 2, head = tid & 3;
    const __half2* hp = h2 + (size_t)n * 64 + head * 16;
    const float* aw = att + head * 64;
    float si = 0.f, sj = 0.f;
    #pragma unroll
    for (int o = 0; o < 16; ++o) {
        float2 hv = __half22float2(hp[o]);
        si += hv.x * aw[2 * o] + hv.y * aw[2 * o + 1];
        sj += hv.x * aw[32 + 2 * o] + hv.y * aw[32 + 2 * o + 1];
    }
    adi[tid] = si;
    adj[tid] = sj;
}

// ---------------------------------------------------------------------------
// CSR build, bucketed counting sort. Bucket = dst>>8 (256 nodes each).
// ---------------------------------------------------------------------------
__global__ __launch_bounds__(256) void k_bin(const int* __restrict__ ei,
                                             int* __restrict__ gcur,
                                             unsigned* __restrict__ bins,
                                             int E, int nbkt, int cap) {
    __shared__ int lcnt[256];
    __shared__ int lbase[256];
    const int t = threadIdx.x;
    if (t < nbkt) lcnt[t] = 0;
    __syncthreads();

    const int e0 = blockIdx.x * 2048;
    const int ne = min(2048, E - e0);

    int bkt[8], rank[8];
    unsigned pk[8];
    #pragma unroll
    for (int k = 0; k < 8; ++k) {
        int idx = t + k * 256;
        if (idx < ne) {
            int e = e0 + idx;
            int src = ei[e], dst = ei[E + e];
            int b = dst >> 8;
            bkt[k] = b;
            pk[k] = ((unsigned)(dst & 255) << 24) | (unsigned)src;
            rank[k] = atomicAdd(&lcnt[b], 1);
        } else bkt[k] = -1;
    }
    __syncthreads();
    if (t < nbkt && lcnt[t] > 0) lbase[t] = atomicAdd(&gcur[t], lcnt[t]);
    __syncthreads();
    #pragma unroll
    for (int k = 0; k < 8; ++k) {
        if (bkt[k] >= 0)
            bins[(size_t)bkt[k] * cap + lbase[bkt[k]] + rank[k]] = pk[k];
    }
}

// one block per bucket. Fused bucket-offset scan (each block recomputes the
// 196-wide prefix of gcur in LDS, ~1us, removes the k_bscan launch).
// Then LDS histogram + scan -> rowoff; LDS cursors -> csr (contiguous region).
__global__ __launch_bounds__(256) void k_bucket(const unsigned* __restrict__ bins,
                                                const int* __restrict__ gcur,
                                                int* __restrict__ rowoff,
                                                int* __restrict__ csr_src,
                                                int N, int cap, int nbkt) {
    __shared__ int cnt[256];
    __shared__ int scn[256];
    __shared__ int cur[256];
    const int b = blockIdx.x, t = threadIdx.x;

    // fused exclusive scan of bucket sizes -> base for this bucket
    int v0 = (t < nbkt) ? gcur[t] : 0;
    scn[t] = v0;
    __syncthreads();
    for (int off = 1; off < 256; off <<= 1) {
        int u = (t >= off) ? scn[t - off] : 0;
        __syncthreads();
        scn[t] += u;
        __syncthreads();
    }
    const int base = (b == 0) ? 0 : scn[b - 1];
    const int sz = gcur[b];
    const unsigned* myb = bins + (size_t)b * cap;
    __syncthreads();

    cnt[t] = 0;
    __syncthreads();
    for (int i = t; i < sz; i += 256) atomicAdd(&cnt[myb[i] >> 24], 1);
    __syncthreads();
    int v = cnt[t];
    scn[t] = v;
    __syncthreads();
    for (int off = 1; off < 256; off <<= 1) {
        int u = (t >= off) ? scn[t - off] : 0;
        __syncthreads();
        scn[t] += u;
        __syncthreads();
    }
    int excl = scn[t] - v;
    int node = b * 256 + t;
    if (node < N) rowoff[node] = base + excl;
    if (node == N - 1) rowoff[N] = base + excl + v;
    cur[t] = excl;
    __syncthreads();
    for (int i = t; i < sz; i += 256) {
        unsigned p = myb[i];
        int pos = atomicAdd(&cur[p >> 24], 1);
        csr_src[base + pos] = (int)(p & 0xFFFFFFu);
    }
}

// ---------------------------------------------------------------------------
// K3: one wave per node, single pass, 8-edge unroll (independent MLP chains),
// 4-wide mid step + scalar tail.
// ---------------------------------------------------------------------------
__global__ __launch_bounds__(256) void k_node(const int* __restrict__ rowoff,
                                              const int* __restrict__ csr_src,
                                              const __half2* __restrict__ h2,
                                              const float* __restrict__ adi,
                                              const float* __restrict__ adjf,
                                              const float* __restrict__ bias,
                                              float* __restrict__ out, int N) {
    int node = (blockIdx.x * blockDim.x + threadIdx.x) >> 6;
    if (node >= N) return;
    const int lane = threadIdx.x & 63;
    const int head = lane >> 4;

    const int beg = rowoff[node];
    const int deg = rowoff[node + 1] - beg;
    const float ai = adi[node * 4 + head];
    const __half2* __restrict__ hb = h2 + lane;

    float acc0 = 0.f, acc1 = 0.f, dsum = 0.f;

    int i = 0;
    for (; i + 8 <= deg; i += 8) {
        int s[8];
        #pragma unroll
        for (int k = 0; k < 8; ++k) s[k] = csr_src[beg + i + k];
        float aj[8];
        #pragma unroll
        for (int k = 0; k < 8; ++k) aj[k] = adjf[s[k] * 4 + head];
        float2 hv[8];
        #pragma unroll
        for (int k = 0; k < 8; ++k) hv[k] = __half22float2(hb[(size_t)s[k] * 64]);
        #pragma unroll
        for (int k = 0; k < 8; ++k) {
            float e = __expf(lrelu(ai + aj[k]));
            dsum += e;
            acc0 += hv[k].x * e;
            acc1 += hv[k].y * e;
        }
    }
    if (i + 4 <= deg) {
        int s[4];
        #pragma unroll
        for (int k = 0; k < 4; ++k) s[k] = csr_src[beg + i + k];
        float aj[4];
        #pragma unroll
        for (int k = 0; k < 4; ++k) aj[k] = adjf[s[k] * 4 + head];
        float2 hv[4];
        #pragma unroll
        for (int k = 0; k < 4; ++k) hv[k] = __half22float2(hb[(size_t)s[k] * 64]);
        #pragma unroll
        for (int k = 0; k < 4; ++k) {
            float e = __expf(lrelu(ai + aj[k]));
            dsum += e;
            acc0 += hv[k].x * e;
            acc1 += hv[k].y * e;
        }
        i += 4;
    }
    for (; i < deg; ++i) {
        int src = csr_src[beg + i];
        float aj = adjf[src * 4 + head];
        float ex = __expf(lrelu(ai + aj));
        dsum += ex;
        float2 hv = __half22float2(hb[(size_t)src * 64]);
        acc0 += hv.x * ex;
        acc1 += hv.y * ex;
    }

    float inv = 1.f / (dsum + 1e-16f);
    float2 bv = ((const float2*)bias)[lane];
    ((float2*)out)[(size_t)node * 64 + lane] =
        make_float2(acc0 * inv + bv.x, acc1 * inv + bv.y);
}

extern "C" void kernel_launch(void* const* d_in, const int* in_sizes, int n_in,
                              void* d_out, int out_size, void* d_ws, size_t ws_size,
                              hipStream_t stream) {
    const float* x    = (const float*)d_in[0];
    const int*   ei   = (const int*)d_in[1];
    const float* w    = (const float*)d_in[2];
    const float* att  = (const float*)d_in[3];
    const float* bias = (const float*)d_in[4];

    const int N = in_sizes[0] / 128;   // 50000
    const int E = in_sizes[1] / 2;     // 800000

    const int NBKT = (N + 255) >> 8;   // 196
    const int CAP  = 8192;

    float* out = (float*)d_out;
    char*  wsb = (char*)d_ws;

    __half* h   = (__half*)wsb;                                // N*128 f16
    float*  adi = (float*)(wsb + (size_t)N * 128 * 2);         // N*4 f
    float*  adj = adi + (size_t)N * 4;                         // N*4 f
    int* rowoff   = (int*)(adj + (size_t)N * 4);               // N+1
    int* csr_src  = rowoff + (N + 1);                          // E
    int* gcur     = csr_src + E;                               // 256
    unsigned* bins = (unsigned*)(gcur + 256);                  // NBKT*CAP

    k_gemm<<<(N + 127) / 128, 256, 0, stream>>>(x, w, h, N);
    k_adot<<<(N * 4 + 255) / 256, 256, 0, stream>>>((const __half2*)h, att, adi, adj, N);

    hipMemsetAsync(gcur, 0, 256 * sizeof(int), stream);
    k_bin<<<(E + 2047) / 2048, 256, 0, stream>>>(ei, gcur, bins, E, NBKT, CAP);
    k_bucket<<<NBKT, 256, 0, stream>>>(bins, gcur, rowoff, csr_src, N, CAP, NBKT);

    {
        long long total = (long long)N * 64;
        int blocks = (int)((total + 255) / 256);
        k_node<<<blocks, 256, 0, stream>>>(rowoff, csr_src, (const __half2*)h,
                                           adi, adj, bias, out, N);
    }
}

// Round 10
// 96.991 us; speedup vs baseline: 2.7840x; 1.0836x over previous
//
#include <hip/hip_runtime.h>
#include <hip/hip_fp16.h>
#include <math.h>

#define NEG_SLOPE 0.2f

typedef __attribute__((ext_vector_type(8))) short bf16x8;
typedef __attribute__((ext_vector_type(4))) short short4v;
typedef __attribute__((ext_vector_type(4))) float f32x4;
typedef __attribute__((ext_vector_type(8))) unsigned short u16x8;

__device__ __forceinline__ float lrelu(float x) { return x > 0.f ? x : NEG_SLOPE * x; }

__device__ __forceinline__ short f2bf(float f) {   // RNE f32 -> bf16
    unsigned u = __float_as_uint(f);
    u += 0x7fff + ((u >> 16) & 1);
    return (short)(u >> 16);
}

// ---------------------------------------------------------------------------
// K1: h = x @ W via MFMA bf16. Block = 128x128 tile, K = 128 one-shot.
// Epilogue: C tile re-staged as f16 in LDS (A-region, free after MFMA) and
// att in B-region -> per-(row,head) attention dots adi/adj computed in-block.
// ---------------------------------------------------------------------------
__global__ __launch_bounds__(256) void k_gemm(const float* __restrict__ x,
                                              const float* __restrict__ w,
                                              const float* __restrict__ att,
                                              __half* __restrict__ hout,
                                              float* __restrict__ adi,
                                              float* __restrict__ adj, int N) {
    __shared__ short SH[32768];           // 64KB: A=[0,16384), B=[16384,32768)
    const int t = threadIdx.x;
    const int row0 = blockIdx.x * 128;

    // stage x -> A region (bf16, xor-swizzled)
    #pragma unroll
    for (int i = 0; i < 16; ++i) {
        int idx = t + 256 * i;
        int r = idx >> 5, c4 = (idx & 31) * 4;
        float4 v = make_float4(0.f, 0.f, 0.f, 0.f);
        if (row0 + r < N) v = *(const float4*)(x + (size_t)(row0 + r) * 128 + c4);
        short4v sv;
        sv.x = f2bf(v.x); sv.y = f2bf(v.y); sv.z = f2bf(v.z); sv.w = f2bf(v.w);
        *(short4v*)&SH[(r * 128 + c4) ^ ((r & 7) << 3)] = sv;
    }
    // stage W^T -> B region
    {
        int c = t & 127, kh = (t >> 7) * 64;
        for (int kb = 0; kb < 16; ++kb) {
            int k = kh + kb * 4;
            short4v sv;
            sv.x = f2bf(w[(size_t)(k + 0) * 128 + c]);
            sv.y = f2bf(w[(size_t)(k + 1) * 128 + c]);
            sv.z = f2bf(w[(size_t)(k + 2) * 128 + c]);
            sv.w = f2bf(w[(size_t)(k + 3) * 128 + c]);
            *(short4v*)&SH[16384 + ((c * 128 + k) ^ ((c & 7) << 3))] = sv;
        }
    }
    __syncthreads();

    const int wv = t >> 6, lane = t & 63;
    const int lr = lane & 15, kg = lane >> 4;

    f32x4 acc[2][8];
    #pragma unroll
    for (int m = 0; m < 2; ++m)
        #pragma unroll
        for (int n = 0; n < 8; ++n) acc[m][n] = (f32x4){0.f, 0.f, 0.f, 0.f};

    #pragma unroll
    for (int kk = 0; kk < 4; ++kk) {
        const int k0 = kk * 32 + kg * 8;
        bf16x8 a[2], b[8];
        #pragma unroll
        for (int m = 0; m < 2; ++m) {
            int r = wv * 32 + m * 16 + lr;
            a[m] = *(const bf16x8*)&SH[(r * 128 + k0) ^ ((r & 7) << 3)];
        }
        #pragma unroll
        for (int n = 0; n < 8; ++n) {
            int c = n * 16 + lr;
            b[n] = *(const bf16x8*)&SH[16384 + ((c * 128 + k0) ^ ((c & 7) << 3))];
        }
        #pragma unroll
        for (int m = 0; m < 2; ++m)
            #pragma unroll
            for (int n = 0; n < 8; ++n)
                acc[m][n] = __builtin_amdgcn_mfma_f32_16x16x32_bf16(a[m], b[n], acc[m][n], 0, 0, 0);
    }

    // global f16 h store (C/D frag: col=lane&15, row=(lane>>4)*4+reg)
    #pragma unroll
    for (int m = 0; m < 2; ++m) {
        #pragma unroll
        for (int reg = 0; reg < 4; ++reg) {
            int r = row0 + wv * 32 + m * 16 + kg * 4 + reg;
            if (r < N) {
                __half* hp = hout + (size_t)r * 128 + lr;
                #pragma unroll
                for (int n = 0; n < 8; ++n)
                    hp[n * 16] = __float2half(acc[m][n][reg]);
            }
        }
    }

    // ---- fused adot epilogue ----
    __syncthreads();                      // A/B fragments fully consumed
    float* attF = (float*)&SH[16384];     // B region bytes [32768,33792)
    attF[t] = att[t];                     // 256 floats
    #pragma unroll
    for (int m = 0; m < 2; ++m)
        #pragma unroll
        for (int reg = 0; reg < 4; ++reg) {
            int row = wv * 32 + m * 16 + kg * 4 + reg;
            #pragma unroll
            for (int n = 0; n < 8; ++n) {
                int col = n * 16 + lr;
                SH[(row * 128 + col) ^ ((row & 7) << 3)] =
                    (short)__half_as_ushort(__float2half(acc[m][n][reg]));
            }
        }
    __syncthreads();
    #pragma unroll
    for (int pp = 0; pp < 2; ++pp) {
        int p = t + pp * 256;             // (row,head) pair 0..511
        int row = p >> 2, head = p & 3;
        int grow = row0 + row;
        if (grow < N) {
            float si = 0.f, sj = 0.f;
            #pragma unroll
            for (int j = 0; j < 32; ++j) {
                int jj = (j + row) & 31;  // rotate to spread LDS banks
                float hv = __half2float(__ushort_as_half(
                    (unsigned short)SH[(row * 128 + head * 32 + jj) ^ ((row & 7) << 3)]));
                si += hv * attF[head * 64 + jj];
                sj += hv * attF[head * 64 + 32 + jj];
            }
            adi[grow * 4 + head] = si;
            adj[grow * 4 + head] = sj;
        }
    }
}

// ---------------------------------------------------------------------------
// CSR build, bucketed counting sort. Bucket = dst>>8 (256 nodes each).
// ---------------------------------------------------------------------------
__global__ __launch_bounds__(256) void k_bin(const int* __restrict__ ei,
                                             int* __restrict__ gcur,
                                             unsigned* __restrict__ bins,
                                             int E, int nbkt, int cap) {
    __shared__ int lcnt[256];
    __shared__ int lbase[256];
    const int t = threadIdx.x;
    if (t < nbkt) lcnt[t] = 0;
    __syncthreads();

    const int e0 = blockIdx.x * 2048;
    const int ne = min(2048, E - e0);

    int bkt[8], rank[8];
    unsigned pk[8];
    #pragma unroll
    for (int k = 0; k < 8; ++k) {
        int idx = t + k * 256;
        if (idx < ne) {
            int e = e0 + idx;
            int src = ei[e], dst = ei[E + e];
            int b = dst >> 8;
            bkt[k] = b;
            pk[k] = ((unsigned)(dst & 255) << 24) | (unsigned)src;
            rank[k] = atomicAdd(&lcnt[b], 1);
        } else bkt[k] = -1;
    }
    __syncthreads();
    if (t < nbkt && lcnt[t] > 0) lbase[t] = atomicAdd(&gcur[t], lcnt[t]);
    __syncthreads();
    #pragma unroll
    for (int k = 0; k < 8; ++k) {
        if (bkt[k] >= 0)
            bins[(size_t)bkt[k] * cap + lbase[bkt[k]] + rank[k]] = pk[k];
    }
}

// one block per bucket; fused bucket-offset scan; LDS cursors -> contiguous csr
__global__ __launch_bounds__(256) void k_bucket(const unsigned* __restrict__ bins,
                                                const int* __restrict__ gcur,
                                                int* __restrict__ rowoff,
                                                int* __restrict__ csr_src,
                                                int N, int cap, int nbkt) {
    __shared__ int cnt[256];
    __shared__ int scn[256];
    __shared__ int cur[256];
    const int b = blockIdx.x, t = threadIdx.x;

    int v0 = (t < nbkt) ? gcur[t] : 0;
    scn[t] = v0;
    __syncthreads();
    for (int off = 1; off < 256; off <<= 1) {
        int u = (t >= off) ? scn[t - off] : 0;
        __syncthreads();
        scn[t] += u;
        __syncthreads();
    }
    const int base = (b == 0) ? 0 : scn[b - 1];
    const int sz = gcur[b];
    const unsigned* myb = bins + (size_t)b * cap;
    __syncthreads();

    cnt[t] = 0;
    __syncthreads();
    for (int i = t; i < sz; i += 256) atomicAdd(&cnt[myb[i] >> 24], 1);
    __syncthreads();
    int v = cnt[t];
    scn[t] = v;
    __syncthreads();
    for (int off = 1; off < 256; off <<= 1) {
        int u = (t >= off) ? scn[t - off] : 0;
        __syncthreads();
        scn[t] += u;
        __syncthreads();
    }
    int excl = scn[t] - v;
    int node = b * 256 + t;
    if (node < N) rowoff[node] = base + excl;
    if (node == N - 1) rowoff[N] = base + excl + v;
    cur[t] = excl;
    __syncthreads();
    for (int i = t; i < sz; i += 256) {
        unsigned p = myb[i];
        int pos = atomicAdd(&cur[p >> 24], 1);
        csr_src[base + pos] = (int)(p & 0xFFFFFFu);
    }
}

// ---------------------------------------------------------------------------
// K3: one wave per node. 16B/lane gathers: quarter q = lane>>4 owns edge q of
// each 4-edge step (x2 steps unrolled = 8 edges in flight). Sublane s = lane&15
// covers output cols 8s..8s+7 (head = s>>2). Quarter-fold via shfl_xor(16,32).
// ---------------------------------------------------------------------------
__global__ __launch_bounds__(256) void k_node(const int* __restrict__ rowoff,
                                              const int* __restrict__ csr_src,
                                              const __half* __restrict__ h,
                                              const float* __restrict__ adi,
                                              const float* __restrict__ adjf,
                                              const float* __restrict__ bias,
                                              float* __restrict__ out, int N) {
    int node = (blockIdx.x * blockDim.x + threadIdx.x) >> 6;
    if (node >= N) return;
    const int lane = threadIdx.x & 63;
    const int q = lane >> 4, s = lane & 15;
    const int head = s >> 2;

    const int beg = rowoff[node];
    const int deg = rowoff[node + 1] - beg;
    const float ai = adi[node * 4 + head];

    float acc[8] = {0.f, 0.f, 0.f, 0.f, 0.f, 0.f, 0.f, 0.f};
    float dsum = 0.f;

    for (int i = 0; i < deg; i += 8) {
        int e0 = i + q, e1 = i + 4 + q;
        int i0 = csr_src[beg + (e0 < deg ? e0 : 0)];
        int i1 = csr_src[beg + (e1 < deg ? e1 : 0)];
        float aj0 = adjf[i0 * 4 + head];
        float aj1 = adjf[i1 * 4 + head];
        u16x8 hv0 = *(const u16x8*)(h + (size_t)i0 * 128 + s * 8);
        u16x8 hv1 = *(const u16x8*)(h + (size_t)i1 * 128 + s * 8);
        float ex0 = (e0 < deg) ? __expf(lrelu(ai + aj0)) : 0.f;
        float ex1 = (e1 < deg) ? __expf(lrelu(ai + aj1)) : 0.f;
        dsum += ex0 + ex1;
        #pragma unroll
        for (int k = 0; k < 8; ++k) {
            acc[k] += __half2float(__ushort_as_half(hv0[k])) * ex0
                    + __half2float(__ushort_as_half(hv1[k])) * ex1;
        }
    }

    #pragma unroll
    for (int k = 0; k < 8; ++k) {
        acc[k] += __shfl_xor(acc[k], 16);
        acc[k] += __shfl_xor(acc[k], 32);
    }
    dsum += __shfl_xor(dsum, 16);
    dsum += __shfl_xor(dsum, 32);

    if (q == 0) {
        float inv = 1.f / (dsum + 1e-16f);
        const float4* b4 = (const float4*)(bias + s * 8);
        float4 bv0 = b4[0], bv1 = b4[1];
        float4 o0 = make_float4(acc[0] * inv + bv0.x, acc[1] * inv + bv0.y,
                                acc[2] * inv + bv0.z, acc[3] * inv + bv0.w);
        float4 o1 = make_float4(acc[4] * inv + bv1.x, acc[5] * inv + bv1.y,
                                acc[6] * inv + bv1.z, acc[7] * inv + bv1.w);
        float4* op = (float4*)(out + (size_t)node * 128 + s * 8);
        op[0] = o0;
        op[1] = o1;
    }
}

extern "C" void kernel_launch(void* const* d_in, const int* in_sizes, int n_in,
                              void* d_out, int out_size, void* d_ws, size_t ws_size,
                              hipStream_t stream) {
    const float* x    = (const float*)d_in[0];
    const int*   ei   = (const int*)d_in[1];
    const float* w    = (const float*)d_in[2];
    const float* att  = (const float*)d_in[3];
    const float* bias = (const float*)d_in[4];

    const int N = in_sizes[0] / 128;   // 50000
    const int E = in_sizes[1] / 2;     // 800000

    const int NBKT = (N + 255) >> 8;   // 196
    const int CAP  = 8192;

    float* out = (float*)d_out;
    char*  wsb = (char*)d_ws;

    __half* h   = (__half*)wsb;                                // N*128 f16
    float*  adi = (float*)(wsb + (size_t)N * 128 * 2);         // N*4 f
    float*  adj = adi + (size_t)N * 4;                         // N*4 f
    int* rowoff   = (int*)(adj + (size_t)N * 4);               // N+1
    int* csr_src  = rowoff + (N + 1);                          // E
    int* gcur     = csr_src + E;                               // 256
    unsigned* bins = (unsigned*)(gcur + 256);                  // NBKT*CAP

    k_gemm<<<(N + 127) / 128, 256, 0, stream>>>(x, w, att, h, adi, adj, N);

    hipMemsetAsync(gcur, 0, 256 * sizeof(int), stream);
    k_bin<<<(E + 2047) / 2048, 256, 0, stream>>>(ei, gcur, bins, E, NBKT, CAP);
    k_bucket<<<NBKT, 256, 0, stream>>>(bins, gcur, rowoff, csr_src, N, CAP, NBKT);

    {
        long long total = (long long)N * 64;
        int blocks = (int)((total + 255) / 256);
        k_node<<<blocks, 256, 0, stream>>>(rowoff, csr_src, (const __half*)h,
                                           adi, adj, bias, out, N);
    }
}

// Round 11
// 84.001 us; speedup vs baseline: 3.2145x; 1.1546x over previous
//
#include <hip/hip_runtime.h>
#include <hip/hip_fp16.h>
#include <math.h>

#define NEG_SLOPE 0.2f

typedef __attribute__((ext_vector_type(8))) short bf16x8;
typedef __attribute__((ext_vector_type(4))) short short4v;
typedef __attribute__((ext_vector_type(4))) float f32x4;
typedef __attribute__((ext_vector_type(8))) unsigned short u16x8;

__device__ __forceinline__ float lrelu(float x) { return x > 0.f ? x : NEG_SLOPE * x; }

__device__ __forceinline__ short f2bf(float f) {   // RNE f32 -> bf16
    unsigned u = __float_as_uint(f);
    u += 0x7fff + ((u >> 16) & 1);
    return (short)(u >> 16);
}

// ---------------------------------------------------------------------------
// K1: h = x @ W via MFMA bf16. Block = 128x128 tile, K = 128 one-shot.
// Epilogue: C tile re-staged as f16 in LDS -> fused adi/adj dots.
// Block 0 also zeroes gcur (removes a memset dispatch before k_bin).
// ---------------------------------------------------------------------------
__global__ __launch_bounds__(256) void k_gemm(const float* __restrict__ x,
                                              const float* __restrict__ w,
                                              const float* __restrict__ att,
                                              __half* __restrict__ hout,
                                              float* __restrict__ adi,
                                              float* __restrict__ adj,
                                              int* __restrict__ gcur, int N) {
    __shared__ short SH[32768];           // 64KB: A=[0,16384), B=[16384,32768)
    const int t = threadIdx.x;
    const int row0 = blockIdx.x * 128;

    if (blockIdx.x == 0) gcur[t] = 0;     // fused CSR-counter zeroing

    // stage x -> A region (bf16, xor-swizzled)
    #pragma unroll
    for (int i = 0; i < 16; ++i) {
        int idx = t + 256 * i;
        int r = idx >> 5, c4 = (idx & 31) * 4;
        float4 v = make_float4(0.f, 0.f, 0.f, 0.f);
        if (row0 + r < N) v = *(const float4*)(x + (size_t)(row0 + r) * 128 + c4);
        short4v sv;
        sv.x = f2bf(v.x); sv.y = f2bf(v.y); sv.z = f2bf(v.z); sv.w = f2bf(v.w);
        *(short4v*)&SH[(r * 128 + c4) ^ ((r & 7) << 3)] = sv;
    }
    // stage W^T -> B region
    {
        int c = t & 127, kh = (t >> 7) * 64;
        for (int kb = 0; kb < 16; ++kb) {
            int k = kh + kb * 4;
            short4v sv;
            sv.x = f2bf(w[(size_t)(k + 0) * 128 + c]);
            sv.y = f2bf(w[(size_t)(k + 1) * 128 + c]);
            sv.z = f2bf(w[(size_t)(k + 2) * 128 + c]);
            sv.w = f2bf(w[(size_t)(k + 3) * 128 + c]);
            *(short4v*)&SH[16384 + ((c * 128 + k) ^ ((c & 7) << 3))] = sv;
        }
    }
    __syncthreads();

    const int wv = t >> 6, lane = t & 63;
    const int lr = lane & 15, kg = lane >> 4;

    f32x4 acc[2][8];
    #pragma unroll
    for (int m = 0; m < 2; ++m)
        #pragma unroll
        for (int n = 0; n < 8; ++n) acc[m][n] = (f32x4){0.f, 0.f, 0.f, 0.f};

    #pragma unroll
    for (int kk = 0; kk < 4; ++kk) {
        const int k0 = kk * 32 + kg * 8;
        bf16x8 a[2], b[8];
        #pragma unroll
        for (int m = 0; m < 2; ++m) {
            int r = wv * 32 + m * 16 + lr;
            a[m] = *(const bf16x8*)&SH[(r * 128 + k0) ^ ((r & 7) << 3)];
        }
        #pragma unroll
        for (int n = 0; n < 8; ++n) {
            int c = n * 16 + lr;
            b[n] = *(const bf16x8*)&SH[16384 + ((c * 128 + k0) ^ ((c & 7) << 3))];
        }
        #pragma unroll
        for (int m = 0; m < 2; ++m)
            #pragma unroll
            for (int n = 0; n < 8; ++n)
                acc[m][n] = __builtin_amdgcn_mfma_f32_16x16x32_bf16(a[m], b[n], acc[m][n], 0, 0, 0);
    }

    // global f16 h store (C/D frag: col=lane&15, row=(lane>>4)*4+reg)
    #pragma unroll
    for (int m = 0; m < 2; ++m) {
        #pragma unroll
        for (int reg = 0; reg < 4; ++reg) {
            int r = row0 + wv * 32 + m * 16 + kg * 4 + reg;
            if (r < N) {
                __half* hp = hout + (size_t)r * 128 + lr;
                #pragma unroll
                for (int n = 0; n < 8; ++n)
                    hp[n * 16] = __float2half(acc[m][n][reg]);
            }
        }
    }

    // ---- fused adot epilogue ----
    __syncthreads();                      // A/B fragments fully consumed
    float* attF = (float*)&SH[16384];     // B region bytes [32768,33792)
    attF[t] = att[t];                     // 256 floats
    #pragma unroll
    for (int m = 0; m < 2; ++m)
        #pragma unroll
        for (int reg = 0; reg < 4; ++reg) {
            int row = wv * 32 + m * 16 + kg * 4 + reg;
            #pragma unroll
            for (int n = 0; n < 8; ++n) {
                int col = n * 16 + lr;
                SH[(row * 128 + col) ^ ((row & 7) << 3)] =
                    (short)__half_as_ushort(__float2half(acc[m][n][reg]));
            }
        }
    __syncthreads();
    #pragma unroll
    for (int pp = 0; pp < 2; ++pp) {
        int p = t + pp * 256;             // (row,head) pair 0..511
        int row = p >> 2, head = p & 3;
        int grow = row0 + row;
        if (grow < N) {
            float si = 0.f, sj = 0.f;
            #pragma unroll
            for (int j = 0; j < 32; ++j) {
                int jj = (j + row) & 31;  // rotate to spread LDS banks
                float hv = __half2float(__ushort_as_half(
                    (unsigned short)SH[(row * 128 + head * 32 + jj) ^ ((row & 7) << 3)]));
                si += hv * attF[head * 64 + jj];
                sj += hv * attF[head * 64 + 32 + jj];
            }
            adi[grow * 4 + head] = si;
            adj[grow * 4 + head] = sj;
        }
    }
}

// ---------------------------------------------------------------------------
// CSR build, bucketed counting sort. Bucket = dst>>8. 4096 edges/block.
// ---------------------------------------------------------------------------
__global__ __launch_bounds__(256) void k_bin(const int* __restrict__ ei,
                                             int* __restrict__ gcur,
                                             unsigned* __restrict__ bins,
                                             int E, int nbkt, int cap) {
    __shared__ int lcnt[256];
    __shared__ int lbase[256];
    const int t = threadIdx.x;
    if (t < nbkt) lcnt[t] = 0;
    __syncthreads();

    const int e0 = blockIdx.x * 4096;
    const int ne = min(4096, E - e0);

    int bkt[16], rank[16];
    unsigned pk[16];
    #pragma unroll
    for (int k = 0; k < 16; ++k) {
        int idx = t + k * 256;
        if (idx < ne) {
            int e = e0 + idx;
            int src = ei[e], dst = ei[E + e];
            int b = dst >> 8;
            bkt[k] = b;
            pk[k] = ((unsigned)(dst & 255) << 24) | (unsigned)src;
            rank[k] = atomicAdd(&lcnt[b], 1);
        } else bkt[k] = -1;
    }
    __syncthreads();
    if (t < nbkt && lcnt[t] > 0) lbase[t] = atomicAdd(&gcur[t], lcnt[t]);
    __syncthreads();
    #pragma unroll
    for (int k = 0; k < 16; ++k) {
        if (bkt[k] >= 0)
            bins[(size_t)bkt[k] * cap + lbase[bkt[k]] + rank[k]] = pk[k];
    }
}

// one block per bucket; fused bucket-offset scan; LDS cursors -> contiguous csr
__global__ __launch_bounds__(256) void k_bucket(const unsigned* __restrict__ bins,
                                                const int* __restrict__ gcur,
                                                int* __restrict__ rowoff,
                                                int* __restrict__ csr_src,
                                                int N, int cap, int nbkt) {
    __shared__ int cnt[256];
    __shared__ int scn[256];
    __shared__ int cur[256];
    const int b = blockIdx.x, t = threadIdx.x;

    int v0 = (t < nbkt) ? gcur[t] : 0;
    scn[t] = v0;
    __syncthreads();
    for (int off = 1; off < 256; off <<= 1) {
        int u = (t >= off) ? scn[t - off] : 0;
        __syncthreads();
        scn[t] += u;
        __syncthreads();
    }
    const int base = (b == 0) ? 0 : scn[b - 1];
    const int sz = gcur[b];
    const unsigned* myb = bins + (size_t)b * cap;
    __syncthreads();

    cnt[t] = 0;
    __syncthreads();
    for (int i = t; i < sz; i += 256) atomicAdd(&cnt[myb[i] >> 24], 1);
    __syncthreads();
    int v = cnt[t];
    scn[t] = v;
    __syncthreads();
    for (int off = 1; off < 256; off <<= 1) {
        int u = (t >= off) ? scn[t - off] : 0;
        __syncthreads();
        scn[t] += u;
        __syncthreads();
    }
    int excl = scn[t] - v;
    int node = b * 256 + t;
    if (node < N) rowoff[node] = base + excl;
    if (node == N - 1) rowoff[N] = base + excl + v;
    cur[t] = excl;
    __syncthreads();
    for (int i = t; i < sz; i += 256) {
        unsigned p = myb[i];
        int pos = atomicAdd(&cur[p >> 24], 1);
        csr_src[base + pos] = (int)(p & 0xFFFFFFu);
    }
}

// ---------------------------------------------------------------------------
// K3: one wave per node. 16B/lane gathers; quarter q owns edge (i+4b+q);
// 16 edges in flight per iteration (4 sub-batches x 4 quarter-edges).
// Sublane s covers cols 8s..8s+7 (head = s>>2). Fold via shfl_xor(16,32).
// ---------------------------------------------------------------------------
__global__ __launch_bounds__(256) void k_node(const int* __restrict__ rowoff,
                                              const int* __restrict__ csr_src,
                                              const __half* __restrict__ h,
                                              const float* __restrict__ adi,
                                              const float* __restrict__ adjf,
                                              const float* __restrict__ bias,
                                              float* __restrict__ out, int N) {
    int node = (blockIdx.x * blockDim.x + threadIdx.x) >> 6;
    if (node >= N) return;
    const int lane = threadIdx.x & 63;
    const int q = lane >> 4, s = lane & 15;
    const int head = s >> 2;

    const int beg = rowoff[node];
    const int deg = rowoff[node + 1] - beg;
    const float ai = adi[node * 4 + head];

    float acc[8] = {0.f, 0.f, 0.f, 0.f, 0.f, 0.f, 0.f, 0.f};
    float dsum = 0.f;

    for (int i = 0; i < deg; i += 16) {
        int idx[4];
        float aj[4];
        u16x8 hv[4];
        // issue all 4 index loads (broadcast lines), then all gathers
        #pragma unroll
        for (int b = 0; b < 4; ++b) {
            int ee = i + 4 * b + q;
            idx[b] = csr_src[beg + (ee < deg ? ee : 0)];
        }
        #pragma unroll
        for (int b = 0; b < 4; ++b) {
            aj[b] = adjf[idx[b] * 4 + head];
            hv[b] = *(const u16x8*)(h + (size_t)idx[b] * 128 + s * 8);
        }
        #pragma unroll
        for (int b = 0; b < 4; ++b) {
            int ee = i + 4 * b + q;
            float ex = (ee < deg) ? __expf(lrelu(ai + aj[b])) : 0.f;
            dsum += ex;
            #pragma unroll
            for (int k = 0; k < 8; ++k)
                acc[k] += __half2float(__ushort_as_half(hv[b][k])) * ex;
        }
    }

    #pragma unroll
    for (int k = 0; k < 8; ++k) {
        acc[k] += __shfl_xor(acc[k], 16);
        acc[k] += __shfl_xor(acc[k], 32);
    }
    dsum += __shfl_xor(dsum, 16);
    dsum += __shfl_xor(dsum, 32);

    if (q == 0) {
        float inv = 1.f / (dsum + 1e-16f);
        const float4* b4 = (const float4*)(bias + s * 8);
        float4 bv0 = b4[0], bv1 = b4[1];
        float4 o0 = make_float4(acc[0] * inv + bv0.x, acc[1] * inv + bv0.y,
                                acc[2] * inv + bv0.z, acc[3] * inv + bv0.w);
        float4 o1 = make_float4(acc[4] * inv + bv1.x, acc[5] * inv + bv1.y,
                                acc[6] * inv + bv1.z, acc[7] * inv + bv1.w);
        float4* op = (float4*)(out + (size_t)node * 128 + s * 8);
        op[0] = o0;
        op[1] = o1;
    }
}

extern "C" void kernel_launch(void* const* d_in, const int* in_sizes, int n_in,
                              void* d_out, int out_size, void* d_ws, size_t ws_size,
                              hipStream_t stream) {
    const float* x    = (const float*)d_in[0];
    const int*   ei   = (const int*)d_in[1];
    const float* w    = (const float*)d_in[2];
    const float* att  = (const float*)d_in[3];
    const float* bias = (const float*)d_in[4];

    const int N = in_sizes[0] / 128;   // 50000
    const int E = in_sizes[1] / 2;     // 800000

    const int NBKT = (N + 255) >> 8;   // 196
    const int CAP  = 8192;

    float* out = (float*)d_out;
    char*  wsb = (char*)d_ws;

    __half* h   = (__half*)wsb;                                // N*128 f16
    float*  adi = (float*)(wsb + (size_t)N * 128 * 2);         // N*4 f
    float*  adj = adi + (size_t)N * 4;                         // N*4 f
    int* rowoff   = (int*)(adj + (size_t)N * 4);               // N+1
    int* csr_src  = rowoff + (N + 1);                          // E
    int* gcur     = csr_src + E;                               // 256
    unsigned* bins = (unsigned*)(gcur + 256);                  // NBKT*CAP

    k_gemm<<<(N + 127) / 128, 256, 0, stream>>>(x, w, att, h, adi, adj, gcur, N);

    k_bin<<<(E + 4095) / 4096, 256, 0, stream>>>(ei, gcur, bins, E, NBKT, CAP);
    k_bucket<<<NBKT, 256, 0, stream>>>(bins, gcur, rowoff, csr_src, N, CAP, NBKT);

    {
        long long total = (long long)N * 64;
        int blocks = (int)((total + 255) / 256);
        k_node<<<blocks, 256, 0, stream>>>(rowoff, csr_src, (const __half*)h,
                                           adi, adj, bias, out, N);
    }
}

// Round 12
// 78.842 us; speedup vs baseline: 3.4249x; 1.0654x over previous
//
#include <hip/hip_runtime.h>
#include <hip/hip_fp16.h>
#include <math.h>

#define NEG_SLOPE 0.2f

typedef __attribute__((ext_vector_type(8))) short bf16x8;
typedef __attribute__((ext_vector_type(4))) short short4v;
typedef __attribute__((ext_vector_type(4))) float f32x4;
typedef __attribute__((ext_vector_type(8))) unsigned short u16x8;

__device__ __forceinline__ float lrelu(float x) { return x > 0.f ? x : NEG_SLOPE * x; }

__device__ __forceinline__ short f2bf(float f) {   // RNE f32 -> bf16
    unsigned u = __float_as_uint(f);
    u += 0x7fff + ((u >> 16) & 1);
    return (short)(u >> 16);
}

// ---------------------------------------------------------------------------
// K1: h = x @ W via MFMA bf16. Block = 64x128 tile, K = 128 one-shot.
// 48KB LDS -> 3 blocks/CU (was 64KB -> 2) for x-staging latency hiding.
// Epilogue: C tile re-staged f16 in A-region -> fused adi/adj dots.
// Block 0 zeroes gcur.
// ---------------------------------------------------------------------------
__global__ __launch_bounds__(256) void k_gemm(const float* __restrict__ x,
                                              const float* __restrict__ w,
                                              const float* __restrict__ att,
                                              __half* __restrict__ hout,
                                              float* __restrict__ adi,
                                              float* __restrict__ adj,
                                              int* __restrict__ gcur, int N) {
    __shared__ short SH[24576];           // 48KB: A=[0,8192), B=[8192,24576)
    const int t = threadIdx.x;
    const int row0 = blockIdx.x * 64;

    if (blockIdx.x == 0) gcur[t] = 0;

    // stage x rows -> A region (bf16, xor-swizzled)
    #pragma unroll
    for (int i = 0; i < 8; ++i) {
        int idx = t + 256 * i;            // float4 slot 0..2047
        int r = idx >> 5, c4 = (idx & 31) * 4;
        float4 v = make_float4(0.f, 0.f, 0.f, 0.f);
        if (row0 + r < N) v = *(const float4*)(x + (size_t)(row0 + r) * 128 + c4);
        short4v sv;
        sv.x = f2bf(v.x); sv.y = f2bf(v.y); sv.z = f2bf(v.z); sv.w = f2bf(v.w);
        *(short4v*)&SH[(r * 128 + c4) ^ ((r & 7) << 3)] = sv;
    }
    // stage W^T -> B region
    {
        int c = t & 127, kh = (t >> 7) * 64;
        for (int kb = 0; kb < 16; ++kb) {
            int k = kh + kb * 4;
            short4v sv;
            sv.x = f2bf(w[(size_t)(k + 0) * 128 + c]);
            sv.y = f2bf(w[(size_t)(k + 1) * 128 + c]);
            sv.z = f2bf(w[(size_t)(k + 2) * 128 + c]);
            sv.w = f2bf(w[(size_t)(k + 3) * 128 + c]);
            *(short4v*)&SH[8192 + ((c * 128 + k) ^ ((c & 7) << 3))] = sv;
        }
    }
    __syncthreads();

    const int wv = t >> 6, lane = t & 63;
    const int lr = lane & 15, kg = lane >> 4;

    f32x4 acc[8];
    #pragma unroll
    for (int n = 0; n < 8; ++n) acc[n] = (f32x4){0.f, 0.f, 0.f, 0.f};

    #pragma unroll
    for (int kk = 0; kk < 4; ++kk) {
        const int k0 = kk * 32 + kg * 8;
        int r = wv * 16 + lr;
        bf16x8 a = *(const bf16x8*)&SH[(r * 128 + k0) ^ ((r & 7) << 3)];
        bf16x8 b[8];
        #pragma unroll
        for (int n = 0; n < 8; ++n) {
            int c = n * 16 + lr;
            b[n] = *(const bf16x8*)&SH[8192 + ((c * 128 + k0) ^ ((c & 7) << 3))];
        }
        #pragma unroll
        for (int n = 0; n < 8; ++n)
            acc[n] = __builtin_amdgcn_mfma_f32_16x16x32_bf16(a, b[n], acc[n], 0, 0, 0);
    }

    // global f16 h store (C/D frag: col=lane&15, row=(lane>>4)*4+reg)
    #pragma unroll
    for (int reg = 0; reg < 4; ++reg) {
        int r = row0 + wv * 16 + kg * 4 + reg;
        if (r < N) {
            __half* hp = hout + (size_t)r * 128 + lr;
            #pragma unroll
            for (int n = 0; n < 8; ++n)
                hp[n * 16] = __float2half(acc[n][reg]);
        }
    }

    // ---- fused adot epilogue ----
    __syncthreads();                      // all fragment reads complete
    float* attF = (float*)&SH[8192];      // 256 floats in (free) B region
    attF[t] = att[t];
    #pragma unroll
    for (int reg = 0; reg < 4; ++reg) {
        int row = wv * 16 + kg * 4 + reg; // local row 0..63
        #pragma unroll
        for (int n = 0; n < 8; ++n) {
            int col = n * 16 + lr;
            SH[(row * 128 + col) ^ ((row & 7) << 3)] =
                (short)__half_as_ushort(__float2half(acc[n][reg]));
        }
    }
    __syncthreads();
    {
        int row = t >> 2, head = t & 3;   // 256 (row,head) pairs
        int grow = row0 + row;
        if (grow < N) {
            float si = 0.f, sj = 0.f;
            #pragma unroll
            for (int j = 0; j < 32; ++j) {
                int jj = (j + row) & 31;  // rotate to spread LDS banks
                float hv = __half2float(__ushort_as_half(
                    (unsigned short)SH[(row * 128 + head * 32 + jj) ^ ((row & 7) << 3)]));
                si += hv * attF[head * 64 + jj];
                sj += hv * attF[head * 64 + 32 + jj];
            }
            adi[grow * 4 + head] = si;
            adj[grow * 4 + head] = sj;
        }
    }
}

// ---------------------------------------------------------------------------
// CSR build, bucketed counting sort. Bucket = dst>>8. 4096 edges/block,
// 512 threads (8 items/thread per phase).
// ---------------------------------------------------------------------------
__global__ __launch_bounds__(512) void k_bin(const int* __restrict__ ei,
                                             int* __restrict__ gcur,
                                             unsigned* __restrict__ bins,
                                             int E, int nbkt, int cap) {
    __shared__ int lcnt[256];
    __shared__ int lbase[256];
    const int t = threadIdx.x;
    if (t < nbkt) lcnt[t] = 0;
    __syncthreads();

    const int e0 = blockIdx.x * 4096;
    const int ne = min(4096, E - e0);

    int bkt[8], rank[8];
    unsigned pk[8];
    #pragma unroll
    for (int k = 0; k < 8; ++k) {
        int idx = t + k * 512;
        if (idx < ne) {
            int e = e0 + idx;
            int src = ei[e], dst = ei[E + e];
            int b = dst >> 8;
            bkt[k] = b;
            pk[k] = ((unsigned)(dst & 255) << 24) | (unsigned)src;
            rank[k] = atomicAdd(&lcnt[b], 1);
        } else bkt[k] = -1;
    }
    __syncthreads();
    if (t < nbkt && lcnt[t] > 0) lbase[t] = atomicAdd(&gcur[t], lcnt[t]);
    __syncthreads();
    #pragma unroll
    for (int k = 0; k < 8; ++k) {
        if (bkt[k] >= 0)
            bins[(size_t)bkt[k] * cap + lbase[bkt[k]] + rank[k]] = pk[k];
    }
}

// one block per bucket, 512 threads; fused bucket-offset scan; LDS cursors.
__global__ __launch_bounds__(512) void k_bucket(const unsigned* __restrict__ bins,
                                                const int* __restrict__ gcur,
                                                int* __restrict__ rowoff,
                                                int* __restrict__ csr_src,
                                                int N, int cap, int nbkt) {
    __shared__ int cnt[256];
    __shared__ int scn[256];
    __shared__ int cur[256];
    const int b = blockIdx.x, t = threadIdx.x;

    if (t < 256) scn[t] = (t < nbkt) ? gcur[t] : 0;
    __syncthreads();
    for (int off = 1; off < 256; off <<= 1) {
        int u = (t < 256 && t >= off) ? scn[t - off] : 0;
        __syncthreads();
        if (t < 256) scn[t] += u;
        __syncthreads();
    }
    const int base = (b == 0) ? 0 : scn[b - 1];
    const int sz = gcur[b];
    const unsigned* myb = bins + (size_t)b * cap;

    if (t < 256) cnt[t] = 0;
    __syncthreads();
    for (int i = t; i < sz; i += 512) atomicAdd(&cnt[myb[i] >> 24], 1);
    __syncthreads();
    int v = (t < 256) ? cnt[t] : 0;
    if (t < 256) scn[t] = v;
    __syncthreads();
    for (int off = 1; off < 256; off <<= 1) {
        int u = (t < 256 && t >= off) ? scn[t - off] : 0;
        __syncthreads();
        if (t < 256) scn[t] += u;
        __syncthreads();
    }
    if (t < 256) {
        int excl = scn[t] - v;
        int node = b * 256 + t;
        if (node < N) rowoff[node] = base + excl;
        if (node == N - 1) rowoff[N] = base + excl + v;
        cur[t] = excl;
    }
    __syncthreads();
    for (int i = t; i < sz; i += 512) {
        unsigned p = myb[i];
        int pos = atomicAdd(&cur[p >> 24], 1);
        csr_src[base + pos] = (int)(p & 0xFFFFFFu);
    }
}

// ---------------------------------------------------------------------------
// K3: one wave per node. 16B/lane gathers; 16 edges in flight per iteration.
// ---------------------------------------------------------------------------
__global__ __launch_bounds__(256) void k_node(const int* __restrict__ rowoff,
                                              const int* __restrict__ csr_src,
                                              const __half* __restrict__ h,
                                              const float* __restrict__ adi,
                                              const float* __restrict__ adjf,
                                              const float* __restrict__ bias,
                                              float* __restrict__ out, int N) {
    int node = (blockIdx.x * blockDim.x + threadIdx.x) >> 6;
    if (node >= N) return;
    const int lane = threadIdx.x & 63;
    const int q = lane >> 4, s = lane & 15;
    const int head = s >> 2;

    const int beg = rowoff[node];
    const int deg = rowoff[node + 1] - beg;
    const float ai = adi[node * 4 + head];

    float acc[8] = {0.f, 0.f, 0.f, 0.f, 0.f, 0.f, 0.f, 0.f};
    float dsum = 0.f;

    for (int i = 0; i < deg; i += 16) {
        int idx[4];
        float aj[4];
        u16x8 hv[4];
        #pragma unroll
        for (int b = 0; b < 4; ++b) {
            int ee = i + 4 * b + q;
            idx[b] = csr_src[beg + (ee < deg ? ee : 0)];
        }
        #pragma unroll
        for (int b = 0; b < 4; ++b) {
            aj[b] = adjf[idx[b] * 4 + head];
            hv[b] = *(const u16x8*)(h + (size_t)idx[b] * 128 + s * 8);
        }
        #pragma unroll
        for (int b = 0; b < 4; ++b) {
            int ee = i + 4 * b + q;
            float ex = (ee < deg) ? __expf(lrelu(ai + aj[b])) : 0.f;
            dsum += ex;
            #pragma unroll
            for (int k = 0; k < 8; ++k)
                acc[k] += __half2float(__ushort_as_half(hv[b][k])) * ex;
        }
    }

    #pragma unroll
    for (int k = 0; k < 8; ++k) {
        acc[k] += __shfl_xor(acc[k], 16);
        acc[k] += __shfl_xor(acc[k], 32);
    }
    dsum += __shfl_xor(dsum, 16);
    dsum += __shfl_xor(dsum, 32);

    if (q == 0) {
        float inv = 1.f / (dsum + 1e-16f);
        const float4* b4 = (const float4*)(bias + s * 8);
        float4 bv0 = b4[0], bv1 = b4[1];
        float4 o0 = make_float4(acc[0] * inv + bv0.x, acc[1] * inv + bv0.y,
                                acc[2] * inv + bv0.z, acc[3] * inv + bv0.w);
        float4 o1 = make_float4(acc[4] * inv + bv1.x, acc[5] * inv + bv1.y,
                                acc[6] * inv + bv1.z, acc[7] * inv + bv1.w);
        float4* op = (float4*)(out + (size_t)node * 128 + s * 8);
        op[0] = o0;
        op[1] = o1;
    }
}

extern "C" void kernel_launch(void* const* d_in, const int* in_sizes, int n_in,
                              void* d_out, int out_size, void* d_ws, size_t ws_size,
                              hipStream_t stream) {
    const float* x    = (const float*)d_in[0];
    const int*   ei   = (const int*)d_in[1];
    const float* w    = (const float*)d_in[2];
    const float* att  = (const float*)d_in[3];
    const float* bias = (const float*)d_in[4];

    const int N = in_sizes[0] / 128;   // 50000
    const int E = in_sizes[1] / 2;     // 800000

    const int NBKT = (N + 255) >> 8;   // 196
    const int CAP  = 8192;

    float* out = (float*)d_out;
    char*  wsb = (char*)d_ws;

    __half* h   = (__half*)wsb;                                // N*128 f16
    float*  adi = (float*)(wsb + (size_t)N * 128 * 2);         // N*4 f
    float*  adj = adi + (size_t)N * 4;                         // N*4 f
    int* rowoff   = (int*)(adj + (size_t)N * 4);               // N+1
    int* csr_src  = rowoff + (N + 1);                          // E
    int* gcur     = csr_src + E;                               // 256
    unsigned* bins = (unsigned*)(gcur + 256);                  // NBKT*CAP

    k_gemm<<<(N + 63) / 64, 256, 0, stream>>>(x, w, att, h, adi, adj, gcur, N);

    k_bin<<<(E + 4095) / 4096, 512, 0, stream>>>(ei, gcur, bins, E, NBKT, CAP);
    k_bucket<<<NBKT, 512, 0, stream>>>(bins, gcur, rowoff, csr_src, N, CAP, NBKT);

    {
        long long total = (long long)N * 64;
        int blocks = (int)((total + 255) / 256);
        k_node<<<blocks, 256, 0, stream>>>(rowoff, csr_src, (const __half*)h,
                                           adi, adj, bias, out, N);
    }
}